// Round 1
// baseline (484.761 us; speedup 1.0000x reference)
//
#include <hip/hip_runtime.h>
#include <math.h>

#define N 8192

// ---------------------------------------------------------------------------
// Kernel A: h = W @ x + b.  One 256-thread block per row, float4 loads.
// Memory-bound: 256 MiB of W at ~6.3 TB/s -> ~42 us floor.
// ---------------------------------------------------------------------------
__global__ __launch_bounds__(256) void matvec_k(const float* __restrict__ W,
                                                const float* __restrict__ x,
                                                const float* __restrict__ b,
                                                float* __restrict__ h) {
  const int row = blockIdx.x;
  const int tid = threadIdx.x;
  const float4* Wr = reinterpret_cast<const float4*>(W + (size_t)row * N);
  const float4* x4 = reinterpret_cast<const float4*>(x);
  float acc = 0.f;
#pragma unroll
  for (int k = 0; k < 8; ++k) {
    const int i = k * 256 + tid;
    const float4 w = Wr[i];
    const float4 xv = x4[i];
    acc = fmaf(w.x, xv.x, acc);
    acc = fmaf(w.y, xv.y, acc);
    acc = fmaf(w.z, xv.z, acc);
    acc = fmaf(w.w, xv.w, acc);
  }
#pragma unroll
  for (int off = 32; off > 0; off >>= 1) acc += __shfl_down(acc, off, 64);
  __shared__ float wsum[4];
  if ((tid & 63) == 0) wsum[tid >> 6] = acc;
  __syncthreads();
  if (tid == 0) h[row] = wsum[0] + wsum[1] + wsum[2] + wsum[3] + b[row];
}

// ---------------------------------------------------------------------------
// Kernel B: budget-constrained softmax over 8192 elements, one 1024-thread
// block. Bitonic sort of (key,idx) packed u64 in LDS; chunked scans for the
// exclusive prefix of cs and inclusive suffix of exp(xs-M); KKT membership
// test; masked softmax; scatter through sort indices.
// ---------------------------------------------------------------------------
__global__ __launch_bounds__(1024) void bcsoftmax_k(const float* __restrict__ h,
                                                    const float* __restrict__ c,
                                                    float* __restrict__ out) {
  __shared__ unsigned long long sb[N];  // 64 KiB: (sortable_key<<32)|idx
  __shared__ float red[1024];           // 4 KiB: scans + reductions
  __shared__ float bcast[4];
  const int tid = threadIdx.x;

  // ---- Phase 0: build sort keys, find global max of h --------------------
  float lmax = -INFINITY;
  for (int g = tid; g < N; g += 1024) {
    const float hv = h[g];
    const float cv = c[g];
    const float key = logf(cv) - hv;  // c==0 -> -inf, sorts first (matches ref)
    unsigned int u = __float_as_uint(key);
    u = (u & 0x80000000u) ? ~u : (u | 0x80000000u);  // float -> sortable uint
    sb[g] = ((unsigned long long)u << 32) | (unsigned int)g;
    lmax = fmaxf(lmax, hv);
  }
#pragma unroll
  for (int off = 32; off > 0; off >>= 1) lmax = fmaxf(lmax, __shfl_down(lmax, off, 64));
  if ((tid & 63) == 0) red[tid >> 6] = lmax;
  __syncthreads();
  if (tid == 0) {
    float mm = red[0];
    for (int i = 1; i < 16; ++i) mm = fmaxf(mm, red[i]);
    bcast[0] = mm;
  }
  __syncthreads();
  const float M = bcast[0];
  __syncthreads();  // sb fully written before sort

  // ---- Phase 1: bitonic sort ascending (stable: idx in low bits) ---------
  for (int k = 2; k <= N; k <<= 1) {
    for (int j = k >> 1; j > 0; j >>= 1) {
      for (int t = tid; t < N; t += 1024) {
        const int ixj = t ^ j;
        if (ixj > t) {
          const unsigned long long a = sb[t];
          const unsigned long long bb = sb[ixj];
          const bool asc = ((t & k) == 0);
          if ((a > bb) == asc) { sb[t] = bb; sb[ixj] = a; }
        }
      }
      __syncthreads();
    }
  }

  // ---- Phase 2: gather sorted xs, cs; local (8-elem chunk) scans ---------
  int   idx[8];
  float xs[8], cs[8], e[8], cpre[8], epre[8];
  float cloc = 0.f, eloc = 0.f;
#pragma unroll
  for (int j = 0; j < 8; ++j) {
    const unsigned long long v = sb[tid * 8 + j];
    const int id = (int)(v & 0xFFFFFFFFull);
    idx[j] = id;
    xs[j] = h[id];
    cs[j] = c[id];
  }
#pragma unroll
  for (int j = 0; j < 8; ++j) {
    e[j] = expf(xs[j] - M);
    cloc += cs[j];  cpre[j] = cloc;   // inclusive local prefix
    eloc += e[j];   epre[j] = eloc;
  }

  // ---- Phase 3a: block inclusive prefix of chunk c-totals ----------------
  __syncthreads();
  red[tid] = cloc;
  __syncthreads();
  for (int off = 1; off < 1024; off <<= 1) {
    const float t = (tid >= off) ? red[tid - off] : 0.f;
    __syncthreads();
    red[tid] += t;
    __syncthreads();
  }
  const float cchunk_excl = red[tid] - cloc;  // sum of c over chunks < tid
  __syncthreads();

  // ---- Phase 3b: block inclusive suffix of chunk e-totals ----------------
  red[tid] = eloc;
  __syncthreads();
  for (int off = 1; off < 1024; off <<= 1) {
    const float t = (tid + off < 1024) ? red[tid + off] : 0.f;
    __syncthreads();
    red[tid] += t;
    __syncthreads();
  }
  const float esuff_incl = red[tid];  // sum of e over chunks >= tid
  __syncthreads();

  // ---- Phase 4: membership test + local reductions -----------------------
  bool kb[8];
  float lm = -INFINITY;  // max xs over mask (= !in_kb)
  float lkbc = 0.f;      // sum cs over in_kb
#pragma unroll
  for (int j = 0; j < 8; ++j) {
    const float s = 1.0f - (cchunk_excl + (cpre[j] - cs[j]));     // 1 - prefix_excl(cs)
    const float suff = esuff_incl - (epre[j] - e[j]);             // suffix_incl(e)
    const float log_r = M + logf(suff);
    const bool in_kb =
        (cs[j] == 0.0f) ||
        ((s - cs[j] > 0.0f) && (xs[j] - log_r + logf(s) > logf(cs[j])));
    kb[j] = in_kb;
    if (in_kb) lkbc += cs[j];
    else       lm = fmaxf(lm, xs[j]);
  }
#pragma unroll
  for (int off = 32; off > 0; off >>= 1) {
    lm = fmaxf(lm, __shfl_down(lm, off, 64));
    lkbc += __shfl_down(lkbc, off, 64);
  }
  if ((tid & 63) == 0) { red[tid >> 6] = lm; red[64 + (tid >> 6)] = lkbc; }
  __syncthreads();
  if (tid == 0) {
    float mm = -INFINITY, sc = 0.f;
    for (int i = 0; i < 16; ++i) { mm = fmaxf(mm, red[i]); sc += red[64 + i]; }
    bcast[1] = mm;
    bcast[2] = 1.0f - sc;  // s2
  }
  __syncthreads();
  const float m = bcast[1];
  const float s2 = bcast[2];

  // ---- Phase 5: r = sum over mask of exp(xs - m) -------------------------
  float lr = 0.f;
#pragma unroll
  for (int j = 0; j < 8; ++j)
    if (!kb[j]) lr += expf(xs[j] - m);
#pragma unroll
  for (int off = 32; off > 0; off >>= 1) lr += __shfl_down(lr, off, 64);
  __syncthreads();
  if ((tid & 63) == 0) red[tid >> 6] = lr;
  __syncthreads();
  if (tid == 0) {
    float rr = 0.f;
    for (int i = 0; i < 16; ++i) rr += red[i];
    bcast[3] = rr;
  }
  __syncthreads();
  const float r = bcast[3];

  // ---- Phase 6: outputs, scattered back through sort indices -------------
#pragma unroll
  for (int j = 0; j < 8; ++j) {
    const float y = kb[j] ? cs[j] : s2 * expf(xs[j] - m) / r;
    out[idx[j]] = y;
  }
}

// ---------------------------------------------------------------------------
extern "C" void kernel_launch(void* const* d_in, const int* in_sizes, int n_in,
                              void* d_out, int out_size, void* d_ws, size_t ws_size,
                              hipStream_t stream) {
  (void)in_sizes; (void)n_in; (void)out_size;
  const float* x = (const float*)d_in[0];
  const float* c = (const float*)d_in[1];
  const float* W = (const float*)d_in[2];
  const float* b = (const float*)d_in[3];
  float* out = (float*)d_out;
  // h scratch: prefer workspace; fall back to d_out (safe: kernel B finishes
  // all reads of h before its final scatter writes, single block + barriers).
  float* h = (ws_size >= (size_t)N * sizeof(float)) ? (float*)d_ws : out;

  matvec_k<<<N, 256, 0, stream>>>(W, x, b, h);
  bcsoftmax_k<<<1, 1024, 0, stream>>>(h, c, out);
}

// Round 2
// 420.285 us; speedup vs baseline: 1.1534x; 1.1534x over previous
//
#include <hip/hip_runtime.h>
#include <math.h>

#define N 8192
typedef unsigned long long u64;

// compare-exchange: ascending if d, descending if !d
#define CE(a, b, d) do { if (((a) > (b)) == (d)) { u64 _t = (a); (a) = (b); (b) = _t; } } while (0)

// ---------------------------------------------------------------------------
// Kernel A: h = W @ x + b.  One WAVE per row: no barriers, shuffle reduce.
// 2048 blocks x 256 threads (4 waves). 268 MB of W at ~6.5 TB/s -> ~42 us.
// ---------------------------------------------------------------------------
__global__ __launch_bounds__(256) void matvec_k(const float* __restrict__ W,
                                                const float* __restrict__ x,
                                                const float* __restrict__ b,
                                                float* __restrict__ h) {
  const int lane = threadIdx.x & 63;
  const int row = blockIdx.x * 4 + (threadIdx.x >> 6);
  const float4* Wr = reinterpret_cast<const float4*>(W + (size_t)row * N);
  const float4* x4 = reinterpret_cast<const float4*>(x);
  float acc = 0.f;
#pragma unroll 8
  for (int k = 0; k < 32; ++k) {
    const int i = k * 64 + lane;
    const float4 w = Wr[i];
    const float4 xv = x4[i];
    acc = fmaf(w.x, xv.x, acc);
    acc = fmaf(w.y, xv.y, acc);
    acc = fmaf(w.z, xv.z, acc);
    acc = fmaf(w.w, xv.w, acc);
  }
#pragma unroll
  for (int off = 32; off > 0; off >>= 1) acc += __shfl_down(acc, off, 64);
  if (lane == 0) h[row] = acc + b[row];
}

// ---------------------------------------------------------------------------
// Kernel B: budget-constrained softmax, one 1024-thread block.
// Register-blocked bitonic sort (contiguous 8-elem ownership): stages k=2,4,8
// and the j=4,2,1 tail of every stage run in registers; LDS passes are
// pair-indexed (half the traffic of element-indexed). Shuffle-based block
// scans (exclusive prefix of c, true exclusive suffix of exp(x-M)).
// ---------------------------------------------------------------------------
__global__ __launch_bounds__(1024) void bcsoftmax_k(const float* __restrict__ h,
                                                    const float* __restrict__ c,
                                                    float* __restrict__ out) {
  __shared__ u64 sb[N];          // 64 KiB: (sortable_key<<32)|idx
  __shared__ float red[32];
  __shared__ float bcast[4];
  const int tid = threadIdx.x;
  const int lane = tid & 63;
  const int wid = tid >> 6;

  u64 v[8];

  // ---- Phase A: load own 8 contiguous elems, build keys, reg-sort k=2,4,8 --
  float hv[8], cv[8];
  {
    const float4* h4 = reinterpret_cast<const float4*>(h);
    const float4* c4 = reinterpret_cast<const float4*>(c);
    const float4 a0 = h4[tid * 2], a1 = h4[tid * 2 + 1];
    const float4 b0 = c4[tid * 2], b1 = c4[tid * 2 + 1];
    hv[0] = a0.x; hv[1] = a0.y; hv[2] = a0.z; hv[3] = a0.w;
    hv[4] = a1.x; hv[5] = a1.y; hv[6] = a1.z; hv[7] = a1.w;
    cv[0] = b0.x; cv[1] = b0.y; cv[2] = b0.z; cv[3] = b0.w;
    cv[4] = b1.x; cv[5] = b1.y; cv[6] = b1.z; cv[7] = b1.w;
  }
  float lmax = -INFINITY;
#pragma unroll
  for (int p = 0; p < 8; ++p) {
    const int g = tid * 8 + p;
    const float key = logf(cv[p]) - hv[p];
    unsigned int u = __float_as_uint(key);
    u = (u & 0x80000000u) ? ~u : (u | 0x80000000u);  // float -> sortable uint
    v[p] = ((u64)u << 32) | (unsigned int)g;
    lmax = fmaxf(lmax, hv[p]);
  }
  // stage k=2 (dir by bit1 of global pos = bit1 of p)
  CE(v[0], v[1], true); CE(v[2], v[3], false); CE(v[4], v[5], true); CE(v[6], v[7], false);
  // stage k=4
  CE(v[0], v[2], true); CE(v[1], v[3], true); CE(v[4], v[6], false); CE(v[5], v[7], false);
  CE(v[0], v[1], true); CE(v[2], v[3], true); CE(v[4], v[5], false); CE(v[6], v[7], false);
  // stage k=8 (dir uniform per thread: bit3 of tid*8 = tid&1)
  {
    const bool d8 = ((tid & 1) == 0);
    CE(v[0], v[4], d8); CE(v[1], v[5], d8); CE(v[2], v[6], d8); CE(v[3], v[7], d8);
    CE(v[0], v[2], d8); CE(v[1], v[3], d8); CE(v[4], v[6], d8); CE(v[5], v[7], d8);
    CE(v[0], v[1], d8); CE(v[2], v[3], d8); CE(v[4], v[5], d8); CE(v[6], v[7], d8);
  }
#pragma unroll
  for (int p = 0; p < 8; ++p) sb[tid * 8 + p] = v[p];

  // global max of h (shuffle + LDS); M consumed much later (after barriers)
#pragma unroll
  for (int off = 32; off > 0; off >>= 1) lmax = fmaxf(lmax, __shfl_down(lmax, off, 64));
  if (lane == 0) red[wid] = lmax;
  __syncthreads();  // also covers sb writes before first LDS pass
  if (tid == 0) {
    float mm = red[0];
    for (int i = 1; i < 16; ++i) mm = fmaxf(mm, red[i]);
    bcast[0] = mm;
  }

  // ---- Phase B: bitonic stages k=16..8192 ---------------------------------
  for (int k = 16;; k <<= 1) {
    for (int j = k >> 1; j >= 8; j >>= 1) {
#pragma unroll
      for (int rep = 0; rep < 4; ++rep) {
        const int i = rep * 1024 + tid;            // pair index, 4096 pairs
        const int t = ((i & ~(j - 1)) << 1) | (i & (j - 1));
        const int p = t | j;
        const u64 a = sb[t];
        const u64 bb = sb[p];
        const bool asc = ((t & k) == 0);
        if ((a > bb) == asc) { sb[t] = bb; sb[p] = a; }
      }
      __syncthreads();
    }
    // register tail: j=4,2,1 (dir uniform per thread for k>=16)
#pragma unroll
    for (int p = 0; p < 8; ++p) v[p] = sb[tid * 8 + p];
    const bool d = (((tid * 8) & k) == 0);
    CE(v[0], v[4], d); CE(v[1], v[5], d); CE(v[2], v[6], d); CE(v[3], v[7], d);
    CE(v[0], v[2], d); CE(v[1], v[3], d); CE(v[4], v[6], d); CE(v[5], v[7], d);
    CE(v[0], v[1], d); CE(v[2], v[3], d); CE(v[4], v[5], d); CE(v[6], v[7], d);
    if (k == N) break;  // final stage: sorted run stays in registers
#pragma unroll
    for (int p = 0; p < 8; ++p) sb[tid * 8 + p] = v[p];
    __syncthreads();
  }

  // ---- Phase C: gather xs, cs; chunk totals -------------------------------
  const float M = bcast[0];
  int idx[8];
  float xs[8], cs[8], e[8];
  float cloc = 0.f, eloc = 0.f;
#pragma unroll
  for (int p = 0; p < 8; ++p) {
    const int id = (int)(v[p] & 0xFFFFFFFFull);
    idx[p] = id;
    xs[p] = h[id];   // L1/L2-hot (read in phase A)
    cs[p] = c[id];
  }
#pragma unroll
  for (int p = 0; p < 8; ++p) {
    e[p] = expf(xs[p] - M);
    cloc += cs[p];
    eloc += e[p];
  }

  // ---- Phase D: block scans via shuffles ----------------------------------
  // exclusive prefix (across threads) of cloc
  float cinc = cloc;
#pragma unroll
  for (int off = 1; off < 64; off <<= 1) {
    const float t = __shfl_up(cinc, off, 64);
    if (lane >= off) cinc += t;
  }
  float cwex = __shfl_up(cinc, 1, 64);
  if (lane == 0) cwex = 0.f;
  __syncthreads();  // red reuse (was lmax partials)
  if (lane == 63) red[wid] = cinc;  // wave totals
  __syncthreads();
  if (tid < 16) {
    float winc = red[tid];
#pragma unroll
    for (int off = 1; off < 16; off <<= 1) {
      const float t = __shfl_up(winc, off, 64);
      if (lane >= off) winc += t;
    }
    float wexc = __shfl_up(winc, 1, 64);
    if (tid == 0) wexc = 0.f;
    red[tid] = wexc;  // exclusive wave offset
  }
  __syncthreads();
  const float cthread_excl = red[wid] + cwex;

  // exclusive suffix (across threads) of eloc — true suffix scan
  float sinc = eloc;
#pragma unroll
  for (int off = 1; off < 64; off <<= 1) {
    const float t = __shfl_down(sinc, off, 64);
    if (lane + off < 64) sinc += t;
  }
  float swex = __shfl_down(sinc, 1, 64);
  if (lane == 63) swex = 0.f;
  __syncthreads();
  if (lane == 0) red[16 + wid] = sinc;  // wave suffix totals
  __syncthreads();
  if (tid < 16) {
    float winc = red[16 + tid];
#pragma unroll
    for (int off = 1; off < 16; off <<= 1) {
      const float t = __shfl_down(winc, off, 64);
      if (tid + off < 16) winc += t;
    }
    float wexc = __shfl_down(winc, 1, 64);
    if (tid == 15) wexc = 0.f;
    red[16 + tid] = wexc;  // exclusive suffix of later waves
  }
  __syncthreads();
  const float ethread_exsuf = red[16 + wid] + swex;

  // ---- Phase E: membership predicate + reductions -------------------------
  float lsuf[8];
  lsuf[7] = e[7];
#pragma unroll
  for (int p = 6; p >= 0; --p) lsuf[p] = e[p] + lsuf[p + 1];
  float cexc = 0.f;
  bool kb[8];
  float lm = -INFINITY, lkbc = 0.f;
#pragma unroll
  for (int p = 0; p < 8; ++p) {
    const float s = 1.0f - (cthread_excl + cexc);
    const float suff = ethread_exsuf + lsuf[p];
    const float log_r = M + logf(suff);
    const bool in_kb =
        (cs[p] == 0.0f) ||
        ((s - cs[p] > 0.0f) && (xs[p] - log_r + logf(s) > logf(cs[p])));
    kb[p] = in_kb;
    if (in_kb) lkbc += cs[p];
    else       lm = fmaxf(lm, xs[p]);
    cexc += cs[p];
  }
#pragma unroll
  for (int off = 32; off > 0; off >>= 1) {
    lm = fmaxf(lm, __shfl_down(lm, off, 64));
    lkbc += __shfl_down(lkbc, off, 64);
  }
  __syncthreads();
  if (lane == 0) { red[wid] = lm; red[16 + wid] = lkbc; }
  __syncthreads();
  if (tid == 0) {
    float mm = red[0], sc = red[16];
    for (int i = 1; i < 16; ++i) { mm = fmaxf(mm, red[i]); sc += red[16 + i]; }
    bcast[1] = mm;
    bcast[2] = 1.0f - sc;  // s2
  }
  __syncthreads();
  const float m = bcast[1];
  const float s2 = bcast[2];

  float lr = 0.f;
#pragma unroll
  for (int p = 0; p < 8; ++p)
    if (!kb[p]) lr += expf(xs[p] - m);
#pragma unroll
  for (int off = 32; off > 0; off >>= 1) lr += __shfl_down(lr, off, 64);
  if (lane == 0) red[wid] = lr;
  __syncthreads();
  if (tid == 0) {
    float rr = red[0];
    for (int i = 1; i < 16; ++i) rr += red[i];
    bcast[3] = rr;
  }
  __syncthreads();
  const float r = bcast[3];

  // ---- Phase F: scatter outputs -------------------------------------------
#pragma unroll
  for (int p = 0; p < 8; ++p) {
    out[idx[p]] = kb[p] ? cs[p] : s2 * expf(xs[p] - m) / r;
  }
}

// ---------------------------------------------------------------------------
extern "C" void kernel_launch(void* const* d_in, const int* in_sizes, int n_in,
                              void* d_out, int out_size, void* d_ws, size_t ws_size,
                              hipStream_t stream) {
  (void)in_sizes; (void)n_in; (void)out_size;
  const float* x = (const float*)d_in[0];
  const float* c = (const float*)d_in[1];
  const float* W = (const float*)d_in[2];
  const float* b = (const float*)d_in[3];
  float* out = (float*)d_out;
  float* h = (ws_size >= (size_t)N * sizeof(float)) ? (float*)d_ws : out;

  matvec_k<<<N / 4, 256, 0, stream>>>(W, x, b, h);
  bcsoftmax_k<<<1, 1024, 0, stream>>>(h, c, out);
}

// Round 3
// 416.095 us; speedup vs baseline: 1.1650x; 1.0101x over previous
//
#include <hip/hip_runtime.h>
#include <math.h>

#define N 8192
typedef unsigned long long u64;

// compare-exchange: ascending if d, descending if !d
#define CE(a, b, d) do { if (((a) > (b)) == (d)) { u64 _t = (a); (a) = (b); (b) = _t; } } while (0)

// ---------------------------------------------------------------------------
// Kernel A: h = W @ x + b.  One WAVE per row, shuffle reduce, no barriers.
// 268 MB of W at ~6.5 TB/s -> ~42 us (memory-roofline).
// ---------------------------------------------------------------------------
__global__ __launch_bounds__(256) void matvec_k(const float* __restrict__ W,
                                                const float* __restrict__ x,
                                                const float* __restrict__ b,
                                                float* __restrict__ h) {
  const int lane = threadIdx.x & 63;
  const int row = blockIdx.x * 4 + (threadIdx.x >> 6);
  const float4* Wr = reinterpret_cast<const float4*>(W + (size_t)row * N);
  const float4* x4 = reinterpret_cast<const float4*>(x);
  float acc = 0.f;
#pragma unroll 8
  for (int k = 0; k < 32; ++k) {
    const int i = k * 64 + lane;
    const float4 w = Wr[i];
    const float4 xv = x4[i];
    acc = fmaf(w.x, xv.x, acc);
    acc = fmaf(w.y, xv.y, acc);
    acc = fmaf(w.z, xv.z, acc);
    acc = fmaf(w.w, xv.w, acc);
  }
#pragma unroll
  for (int off = 32; off > 0; off >>= 1) acc += __shfl_down(acc, off, 64);
  if (lane == 0) h[row] = acc + b[row];
}

// ---------------------------------------------------------------------------
// Kernel B: budget-constrained softmax, one 1024-thread block.
// Hybrid bitonic: 8 elems/thread => a wave owns 512 contiguous elements, so
// steps j=8..256 are intra-wave shfl_xor (no LDS, no barriers); only
// j=512..4096 touch LDS (10 b128 pair-passes, ~14 barriers vs 55 before).
// h/c staged in LDS so the post-sort gather and output scatter avoid
// 64-way-split global transactions.
// ---------------------------------------------------------------------------
__global__ __launch_bounds__(1024) void bcsoftmax_k(const float* __restrict__ h,
                                                    const float* __restrict__ c,
                                                    float* __restrict__ out) {
  __shared__ u64 sb[N];       // 64 KiB: (sortable_key<<32)|idx
  __shared__ float hbuf[N];   // 32 KiB (reused as ybuf at the end)
  __shared__ float cbuf[N];   // 32 KiB
  __shared__ float red[32];
  __shared__ float bcast[4];
  const int tid = threadIdx.x;
  const int lane = tid & 63;
  const int wid = tid >> 6;

  u64 v[8];

  // ---- Phase A: coalesced load, stage h/c to LDS, build keys --------------
  float hv[8], cv[8];
  {
    const float4* h4 = reinterpret_cast<const float4*>(h);
    const float4* c4 = reinterpret_cast<const float4*>(c);
    const float4 a0 = h4[tid * 2], a1 = h4[tid * 2 + 1];
    const float4 b0 = c4[tid * 2], b1 = c4[tid * 2 + 1];
    reinterpret_cast<float4*>(hbuf)[tid * 2]     = a0;
    reinterpret_cast<float4*>(hbuf)[tid * 2 + 1] = a1;
    reinterpret_cast<float4*>(cbuf)[tid * 2]     = b0;
    reinterpret_cast<float4*>(cbuf)[tid * 2 + 1] = b1;
    hv[0] = a0.x; hv[1] = a0.y; hv[2] = a0.z; hv[3] = a0.w;
    hv[4] = a1.x; hv[5] = a1.y; hv[6] = a1.z; hv[7] = a1.w;
    cv[0] = b0.x; cv[1] = b0.y; cv[2] = b0.z; cv[3] = b0.w;
    cv[4] = b1.x; cv[5] = b1.y; cv[6] = b1.z; cv[7] = b1.w;
  }
  float lmax = -INFINITY;
#pragma unroll
  for (int p = 0; p < 8; ++p) {
    const int g = tid * 8 + p;
    const float key = logf(cv[p]) - hv[p];
    unsigned int u = __float_as_uint(key);
    u = (u & 0x80000000u) ? ~u : (u | 0x80000000u);  // float -> sortable uint
    v[p] = ((u64)u << 32) | (unsigned int)g;
    lmax = fmaxf(lmax, hv[p]);
  }
#pragma unroll
  for (int off = 32; off > 0; off >>= 1) lmax = fmaxf(lmax, __shfl_down(lmax, off, 64));
  if (lane == 0) red[wid] = lmax;   // consumed by tid 0 after first barrier

  // ---- register sort: stages k=2,4,8 --------------------------------------
  CE(v[0], v[1], true); CE(v[2], v[3], false); CE(v[4], v[5], true); CE(v[6], v[7], false);
  CE(v[0], v[2], true); CE(v[1], v[3], true); CE(v[4], v[6], false); CE(v[5], v[7], false);
  CE(v[0], v[1], true); CE(v[2], v[3], true); CE(v[4], v[5], false); CE(v[6], v[7], false);
  {
    const bool d8 = ((tid & 1) == 0);
    CE(v[0], v[4], d8); CE(v[1], v[5], d8); CE(v[2], v[6], d8); CE(v[3], v[7], d8);
    CE(v[0], v[2], d8); CE(v[1], v[3], d8); CE(v[4], v[6], d8); CE(v[5], v[7], d8);
    CE(v[0], v[1], d8); CE(v[2], v[3], d8); CE(v[4], v[5], d8); CE(v[6], v[7], d8);
  }

  // ---- stages k=16..512: pure intra-wave (shfl_xor + register tail) -------
  for (int k = 16; k <= 512; k <<= 1) {
    const bool asc = (((tid * 8) & k) == 0);
    for (int j = k >> 1; j >= 8; j >>= 1) {
      const int d = j >> 3;
      const bool keepmin = (((lane & d) == 0) == asc);
#pragma unroll
      for (int p = 0; p < 8; ++p) {
        const u64 o = __shfl_xor(v[p], d, 64);
        const bool take = keepmin ? (o < v[p]) : (o > v[p]);
        if (take) v[p] = o;
      }
    }
    CE(v[0], v[4], asc); CE(v[1], v[5], asc); CE(v[2], v[6], asc); CE(v[3], v[7], asc);
    CE(v[0], v[2], asc); CE(v[1], v[3], asc); CE(v[4], v[6], asc); CE(v[5], v[7], asc);
    CE(v[0], v[1], asc); CE(v[2], v[3], asc); CE(v[4], v[5], asc); CE(v[6], v[7], asc);
  }

  // ---- stages k=1024..8192: LDS for j>=512, shfl for j=256..8, reg tail ---
  for (int k = 1024; k <= N; k <<= 1) {
#pragma unroll
    for (int p = 0; p < 8; p += 2) {
      ulonglong2 t2; t2.x = v[p]; t2.y = v[p + 1];
      *reinterpret_cast<ulonglong2*>(&sb[tid * 8 + p]) = t2;
    }
    __syncthreads();
    if (k == 1024 && tid == 0) {  // finish global max of h (red written pre-barrier)
      float mm = red[0];
      for (int i = 1; i < 16; ++i) mm = fmaxf(mm, red[i]);
      bcast[0] = mm;
    }
    for (int j = k >> 1; j >= 512; j >>= 1) {
      const int jh = j >> 1;
#pragma unroll
      for (int rep = 0; rep < 2; ++rep) {
        const int q = rep * 1024 + tid;
        const int u = ((q & ~(jh - 1)) << 1) | (q & (jh - 1));  // (u & jh)==0
        const int t = u * 2;                                     // (t & j)==0, even
        const bool asc = ((t & k) == 0);
        ulonglong2 A = *reinterpret_cast<ulonglong2*>(&sb[t]);
        ulonglong2 B = *reinterpret_cast<ulonglong2*>(&sb[t + j]);
        CE(A.x, B.x, asc); CE(A.y, B.y, asc);
        *reinterpret_cast<ulonglong2*>(&sb[t]) = A;
        *reinterpret_cast<ulonglong2*>(&sb[t + j]) = B;
      }
      __syncthreads();
    }
#pragma unroll
    for (int p = 0; p < 8; p += 2) {
      const ulonglong2 t2 = *reinterpret_cast<ulonglong2*>(&sb[tid * 8 + p]);
      v[p] = t2.x; v[p + 1] = t2.y;
    }
    const bool asc = (((tid * 8) & k) == 0);
    for (int j = 256; j >= 8; j >>= 1) {
      const int d = j >> 3;
      const bool keepmin = (((lane & d) == 0) == asc);
#pragma unroll
      for (int p = 0; p < 8; ++p) {
        const u64 o = __shfl_xor(v[p], d, 64);
        const bool take = keepmin ? (o < v[p]) : (o > v[p]);
        if (take) v[p] = o;
      }
    }
    CE(v[0], v[4], asc); CE(v[1], v[5], asc); CE(v[2], v[6], asc); CE(v[3], v[7], asc);
    CE(v[0], v[2], asc); CE(v[1], v[3], asc); CE(v[4], v[6], asc); CE(v[5], v[7], asc);
    CE(v[0], v[1], asc); CE(v[2], v[3], asc); CE(v[4], v[5], asc); CE(v[6], v[7], asc);
  }
  // v[] now holds the fully sorted records (ascending).

  // ---- Phase C: gather xs, cs from LDS; chunk totals ----------------------
  const float M = bcast[0];
  int idx[8];
  float xs[8], cs[8], e[8];
  float cloc = 0.f, eloc = 0.f;
#pragma unroll
  for (int p = 0; p < 8; ++p) {
    const int id = (int)(v[p] & 0xFFFFFFFFull);
    idx[p] = id;
    xs[p] = hbuf[id];
    cs[p] = cbuf[id];
  }
#pragma unroll
  for (int p = 0; p < 8; ++p) {
    e[p] = expf(xs[p] - M);
    cloc += cs[p];
    eloc += e[p];
  }

  // ---- Phase D: block scans via shuffles ----------------------------------
  float cinc = cloc;
#pragma unroll
  for (int off = 1; off < 64; off <<= 1) {
    const float t = __shfl_up(cinc, off, 64);
    if (lane >= off) cinc += t;
  }
  float cwex = __shfl_up(cinc, 1, 64);
  if (lane == 0) cwex = 0.f;
  __syncthreads();
  if (lane == 63) red[wid] = cinc;  // wave totals
  __syncthreads();
  if (tid < 16) {
    float winc = red[tid];
#pragma unroll
    for (int off = 1; off < 16; off <<= 1) {
      const float t = __shfl_up(winc, off, 64);
      if (lane >= off) winc += t;
    }
    float wexc = __shfl_up(winc, 1, 64);
    if (tid == 0) wexc = 0.f;
    red[tid] = wexc;
  }
  __syncthreads();
  const float cthread_excl = red[wid] + cwex;

  float sinc = eloc;
#pragma unroll
  for (int off = 1; off < 64; off <<= 1) {
    const float t = __shfl_down(sinc, off, 64);
    if (lane + off < 64) sinc += t;
  }
  float swex = __shfl_down(sinc, 1, 64);
  if (lane == 63) swex = 0.f;
  __syncthreads();
  if (lane == 0) red[16 + wid] = sinc;  // wave suffix totals
  __syncthreads();
  if (tid < 16) {
    float winc = red[16 + tid];
#pragma unroll
    for (int off = 1; off < 16; off <<= 1) {
      const float t = __shfl_down(winc, off, 64);
      if (tid + off < 16) winc += t;
    }
    float wexc = __shfl_down(winc, 1, 64);
    if (tid == 15) wexc = 0.f;
    red[16 + tid] = wexc;
  }
  __syncthreads();
  const float ethread_exsuf = red[16 + wid] + swex;

  // ---- Phase E: membership predicate + reductions -------------------------
  float lsuf[8];
  lsuf[7] = e[7];
#pragma unroll
  for (int p = 6; p >= 0; --p) lsuf[p] = e[p] + lsuf[p + 1];
  float cexc = 0.f;
  bool kb[8];
  float lm = -INFINITY, lkbc = 0.f;
#pragma unroll
  for (int p = 0; p < 8; ++p) {
    const float s = 1.0f - (cthread_excl + cexc);
    const float suff = ethread_exsuf + lsuf[p];
    const float log_r = M + logf(suff);
    const bool in_kb =
        (cs[p] == 0.0f) ||
        ((s - cs[p] > 0.0f) && (xs[p] - log_r + logf(s) > logf(cs[p])));
    kb[p] = in_kb;
    if (in_kb) lkbc += cs[p];
    else       lm = fmaxf(lm, xs[p]);
    cexc += cs[p];
  }
#pragma unroll
  for (int off = 32; off > 0; off >>= 1) {
    lm = fmaxf(lm, __shfl_down(lm, off, 64));
    lkbc += __shfl_down(lkbc, off, 64);
  }
  __syncthreads();
  if (lane == 0) { red[wid] = lm; red[16 + wid] = lkbc; }
  __syncthreads();
  if (tid == 0) {
    float mm = red[0], sc = red[16];
    for (int i = 1; i < 16; ++i) { mm = fmaxf(mm, red[i]); sc += red[16 + i]; }
    bcast[1] = mm;
    bcast[2] = 1.0f - sc;  // s2
  }
  __syncthreads();
  const float m = bcast[1];
  const float s2 = bcast[2];

  float ey[8];
  float lr = 0.f;
#pragma unroll
  for (int p = 0; p < 8; ++p) {
    ey[p] = expf(xs[p] - m);
    if (!kb[p]) lr += ey[p];
  }
#pragma unroll
  for (int off = 32; off > 0; off >>= 1) lr += __shfl_down(lr, off, 64);
  if (lane == 0) red[wid] = lr;
  __syncthreads();
  if (tid == 0) {
    float rr = red[0];
    for (int i = 1; i < 16; ++i) rr += red[i];
    bcast[3] = rr;
  }
  __syncthreads();
  const float r = bcast[3];

  // ---- Phase F: scatter to LDS, then coalesced global store ---------------
  float* ybuf = hbuf;  // hbuf no longer needed
#pragma unroll
  for (int p = 0; p < 8; ++p) {
    ybuf[idx[p]] = kb[p] ? cs[p] : s2 * ey[p] / r;
  }
  __syncthreads();
  {
    const float4* y4 = reinterpret_cast<const float4*>(ybuf);
    float4* o4 = reinterpret_cast<float4*>(out);
    o4[tid * 2]     = y4[tid * 2];
    o4[tid * 2 + 1] = y4[tid * 2 + 1];
  }
}

// ---------------------------------------------------------------------------
extern "C" void kernel_launch(void* const* d_in, const int* in_sizes, int n_in,
                              void* d_out, int out_size, void* d_ws, size_t ws_size,
                              hipStream_t stream) {
  (void)in_sizes; (void)n_in; (void)out_size;
  const float* x = (const float*)d_in[0];
  const float* c = (const float*)d_in[1];
  const float* W = (const float*)d_in[2];
  const float* b = (const float*)d_in[3];
  float* out = (float*)d_out;
  float* h = (ws_size >= (size_t)N * sizeof(float)) ? (float*)d_ws : out;

  matvec_k<<<N / 4, 256, 0, stream>>>(W, x, b, h);
  bcsoftmax_k<<<1, 1024, 0, stream>>>(h, c, out);
}

// Round 4
// 409.235 us; speedup vs baseline: 1.1846x; 1.0168x over previous
//
#include <hip/hip_runtime.h>
#include <math.h>

#define N 8192
typedef unsigned long long u64;

// ---------------------------------------------------------------------------
// Kernel A: h = W @ x + b, one WAVE per row (no barriers), plus emit the
// stable-sort record Kkey[row] = (sortable_u32(log(c)-h) << 13) | row.
// 268 MB of W at ~6.5 TB/s -> ~42 us (memory roofline).
// ---------------------------------------------------------------------------
__global__ __launch_bounds__(256) void matvec_k(const float* __restrict__ W,
                                                const float* __restrict__ x,
                                                const float* __restrict__ b,
                                                const float* __restrict__ c,
                                                float* __restrict__ h,
                                                u64* __restrict__ Kkey) {
  const int lane = threadIdx.x & 63;
  const int row = blockIdx.x * 4 + (threadIdx.x >> 6);
  const float4* Wr = reinterpret_cast<const float4*>(W + (size_t)row * N);
  const float4* x4 = reinterpret_cast<const float4*>(x);
  float acc = 0.f;
#pragma unroll 8
  for (int k = 0; k < 32; ++k) {
    const int i = k * 64 + lane;
    const float4 w = Wr[i];
    const float4 xv = x4[i];
    acc = fmaf(w.x, xv.x, acc);
    acc = fmaf(w.y, xv.y, acc);
    acc = fmaf(w.z, xv.z, acc);
    acc = fmaf(w.w, xv.w, acc);
  }
#pragma unroll
  for (int off = 32; off > 0; off >>= 1) acc += __shfl_down(acc, off, 64);
  if (lane == 0) {
    const float hv = acc + b[row];
    h[row] = hv;
    const float key = logf(c[row]) - hv;  // c==0 -> -inf, sorts first
    unsigned int u = __float_as_uint(key);
    u = (u & 0x80000000u) ? ~u : (u | 0x80000000u);  // float -> sortable uint
    Kkey[row] = ((u64)u << 13) | (unsigned int)row;  // row < 8192 = 2^13
  }
}

// ---------------------------------------------------------------------------
// Kernel B: partial ranks. Grid (32 element-groups, 8 key-chunks) x 256 thr.
// Each thread owns one element i and counts Kkey[j] < Kkey[i] over a
// 1024-key chunk. Chunk reads are wave-uniform -> scalar-cache loads.
// ---------------------------------------------------------------------------
__global__ __launch_bounds__(256) void rank_k(const u64* __restrict__ Kkey,
                                              unsigned int* __restrict__ partial) {
  const int i = blockIdx.x * 256 + threadIdx.x;
  const u64 Ki = Kkey[i];
  const u64* __restrict__ Kc = Kkey + blockIdx.y * 1024;
  unsigned int cnt = 0;
#pragma unroll 8
  for (int t = 0; t < 1024; ++t) cnt += (Kc[t] < Ki) ? 1u : 0u;
  partial[blockIdx.y * N + i] = cnt;
}

// ---------------------------------------------------------------------------
// Kernel C: budget-constrained softmax, one 1024-thread block, NO SORT.
// Sums the 8 rank partials per element, scatters sperm[rank]=elem in LDS,
// then runs the scan/predicate/output phases (bit-identical arithmetic to
// the verified R2 kernel -> absmax 0.0 preserved).
// ---------------------------------------------------------------------------
__global__ __launch_bounds__(1024) void bcsoftmax_k(const float* __restrict__ h,
                                                    const float* __restrict__ c,
                                                    const unsigned int* __restrict__ partial,
                                                    float* __restrict__ out) {
  __shared__ float hbuf[N];          // 32 KiB (reused as ybuf at the end)
  __shared__ float cbuf[N];          // 32 KiB
  __shared__ unsigned int sperm[N];  // 32 KiB: sorted pos -> original idx
  __shared__ float red[32];
  __shared__ float bcast[4];
  const int tid = threadIdx.x;
  const int lane = tid & 63;
  const int wid = tid >> 6;

  // ---- Phase 0a: coalesced stage of h, c into LDS; running max of h -------
  float lmax = -INFINITY;
  {
    const float4* h4 = reinterpret_cast<const float4*>(h);
    const float4* c4 = reinterpret_cast<const float4*>(c);
    const float4 a0 = h4[tid * 2], a1 = h4[tid * 2 + 1];
    const float4 b0 = c4[tid * 2], b1 = c4[tid * 2 + 1];
    reinterpret_cast<float4*>(hbuf)[tid * 2]     = a0;
    reinterpret_cast<float4*>(hbuf)[tid * 2 + 1] = a1;
    reinterpret_cast<float4*>(cbuf)[tid * 2]     = b0;
    reinterpret_cast<float4*>(cbuf)[tid * 2 + 1] = b1;
    lmax = fmaxf(lmax, fmaxf(fmaxf(a0.x, a0.y), fmaxf(a0.z, a0.w)));
    lmax = fmaxf(lmax, fmaxf(fmaxf(a1.x, a1.y), fmaxf(a1.z, a1.w)));
  }
#pragma unroll
  for (int off = 32; off > 0; off >>= 1) lmax = fmaxf(lmax, __shfl_down(lmax, off, 64));
  if (lane == 0) red[wid] = lmax;

  // ---- Phase 0b: sum rank partials, scatter permutation into LDS ----------
#pragma unroll
  for (int p = 0; p < 8; ++p) {
    const int g = p * 1024 + tid;  // coalesced ownership for partial reads
    unsigned int rank = 0;
#pragma unroll
    for (int y = 0; y < 8; ++y) rank += partial[y * N + g];
    sperm[rank] = (unsigned int)g;
  }
  __syncthreads();  // hbuf, cbuf, sperm, red all visible
  if (tid == 0) {
    float mm = red[0];
    for (int i = 1; i < 16; ++i) mm = fmaxf(mm, red[i]);
    bcast[0] = mm;
  }
  __syncthreads();
  const float M = bcast[0];

  // ---- Phase C: gather sorted xs, cs from LDS; chunk totals ---------------
  int idx[8];
  float xs[8], cs[8], e[8];
  float cloc = 0.f, eloc = 0.f;
  {
    const uint4* sp4 = reinterpret_cast<const uint4*>(sperm);
    const uint4 i0 = sp4[tid * 2], i1 = sp4[tid * 2 + 1];
    idx[0] = i0.x; idx[1] = i0.y; idx[2] = i0.z; idx[3] = i0.w;
    idx[4] = i1.x; idx[5] = i1.y; idx[6] = i1.z; idx[7] = i1.w;
  }
#pragma unroll
  for (int p = 0; p < 8; ++p) {
    xs[p] = hbuf[idx[p]];
    cs[p] = cbuf[idx[p]];
  }
#pragma unroll
  for (int p = 0; p < 8; ++p) {
    e[p] = expf(xs[p] - M);
    cloc += cs[p];
    eloc += e[p];
  }

  // ---- Phase D: block scans via shuffles ----------------------------------
  float cinc = cloc;
#pragma unroll
  for (int off = 1; off < 64; off <<= 1) {
    const float t = __shfl_up(cinc, off, 64);
    if (lane >= off) cinc += t;
  }
  float cwex = __shfl_up(cinc, 1, 64);
  if (lane == 0) cwex = 0.f;
  __syncthreads();  // red reuse (was lmax partials)
  if (lane == 63) red[wid] = cinc;  // wave totals
  __syncthreads();
  if (tid < 16) {
    float winc = red[tid];
#pragma unroll
    for (int off = 1; off < 16; off <<= 1) {
      const float t = __shfl_up(winc, off, 64);
      if (lane >= off) winc += t;
    }
    float wexc = __shfl_up(winc, 1, 64);
    if (tid == 0) wexc = 0.f;
    red[tid] = wexc;
  }
  __syncthreads();
  const float cthread_excl = red[wid] + cwex;

  float sinc = eloc;
#pragma unroll
  for (int off = 1; off < 64; off <<= 1) {
    const float t = __shfl_down(sinc, off, 64);
    if (lane + off < 64) sinc += t;
  }
  float swex = __shfl_down(sinc, 1, 64);
  if (lane == 63) swex = 0.f;
  __syncthreads();
  if (lane == 0) red[16 + wid] = sinc;  // wave suffix totals
  __syncthreads();
  if (tid < 16) {
    float winc = red[16 + tid];
#pragma unroll
    for (int off = 1; off < 16; off <<= 1) {
      const float t = __shfl_down(winc, off, 64);
      if (tid + off < 16) winc += t;
    }
    float wexc = __shfl_down(winc, 1, 64);
    if (tid == 15) wexc = 0.f;
    red[16 + tid] = wexc;
  }
  __syncthreads();
  const float ethread_exsuf = red[16 + wid] + swex;

  // ---- Phase E: membership predicate + reductions -------------------------
  float lsuf[8];
  lsuf[7] = e[7];
#pragma unroll
  for (int p = 6; p >= 0; --p) lsuf[p] = e[p] + lsuf[p + 1];
  float cexc = 0.f;
  bool kb[8];
  float lm = -INFINITY, lkbc = 0.f;
#pragma unroll
  for (int p = 0; p < 8; ++p) {
    const float s = 1.0f - (cthread_excl + cexc);
    const float suff = ethread_exsuf + lsuf[p];
    const float log_r = M + logf(suff);
    const bool in_kb =
        (cs[p] == 0.0f) ||
        ((s - cs[p] > 0.0f) && (xs[p] - log_r + logf(s) > logf(cs[p])));
    kb[p] = in_kb;
    if (in_kb) lkbc += cs[p];
    else       lm = fmaxf(lm, xs[p]);
    cexc += cs[p];
  }
#pragma unroll
  for (int off = 32; off > 0; off >>= 1) {
    lm = fmaxf(lm, __shfl_down(lm, off, 64));
    lkbc += __shfl_down(lkbc, off, 64);
  }
  __syncthreads();
  if (lane == 0) { red[wid] = lm; red[16 + wid] = lkbc; }
  __syncthreads();
  if (tid == 0) {
    float mm = red[0], sc = red[16];
    for (int i = 1; i < 16; ++i) { mm = fmaxf(mm, red[i]); sc += red[16 + i]; }
    bcast[1] = mm;
    bcast[2] = 1.0f - sc;  // s2
  }
  __syncthreads();
  const float m = bcast[1];
  const float s2 = bcast[2];

  float ey[8];
  float lr = 0.f;
#pragma unroll
  for (int p = 0; p < 8; ++p) {
    ey[p] = expf(xs[p] - m);
    if (!kb[p]) lr += ey[p];
  }
#pragma unroll
  for (int off = 32; off > 0; off >>= 1) lr += __shfl_down(lr, off, 64);
  if (lane == 0) red[wid] = lr;
  __syncthreads();
  if (tid == 0) {
    float rr = red[0];
    for (int i = 1; i < 16; ++i) rr += red[i];
    bcast[3] = rr;
  }
  __syncthreads();
  const float r = bcast[3];

  // ---- Phase F: scatter to LDS, then coalesced global store ---------------
  float* ybuf = hbuf;  // hbuf no longer needed
#pragma unroll
  for (int p = 0; p < 8; ++p) {
    ybuf[idx[p]] = kb[p] ? cs[p] : s2 * ey[p] / r;
  }
  __syncthreads();
  {
    const float4* y4 = reinterpret_cast<const float4*>(ybuf);
    float4* o4 = reinterpret_cast<float4*>(out);
    o4[tid * 2]     = y4[tid * 2];
    o4[tid * 2 + 1] = y4[tid * 2 + 1];
  }
}

// ---------------------------------------------------------------------------
extern "C" void kernel_launch(void* const* d_in, const int* in_sizes, int n_in,
                              void* d_out, int out_size, void* d_ws, size_t ws_size,
                              hipStream_t stream) {
  (void)in_sizes; (void)n_in; (void)out_size; (void)ws_size;
  const float* x = (const float*)d_in[0];
  const float* c = (const float*)d_in[1];
  const float* W = (const float*)d_in[2];
  const float* b = (const float*)d_in[3];
  float* out = (float*)d_out;

  // ws layout: h (32 KB) | Kkey (64 KB) | partial (256 KB)
  char* ws = (char*)d_ws;
  float* h = (float*)ws;
  u64* Kkey = (u64*)(ws + 32768);
  unsigned int* partial = (unsigned int*)(ws + 32768 + 65536);

  matvec_k<<<N / 4, 256, 0, stream>>>(W, x, b, c, h, Kkey);
  rank_k<<<dim3(32, 8), 256, 0, stream>>>(Kkey, partial);
  bcsoftmax_k<<<1, 1024, 0, stream>>>(h, c, partial, out);
}

// Round 5
// 408.448 us; speedup vs baseline: 1.1868x; 1.0019x over previous
//
#include <hip/hip_runtime.h>
#include <math.h>

#define N 8192
typedef unsigned long long u64;

// ---------------------------------------------------------------------------
// Kernel A: h = W @ x + b (+ emit stable-sort key record).
// 1024-thread blocks, 16 waves = 16 rows per block, x staged ONCE per block
// in LDS (kills the 268 MB x re-read stream through L1/L2), 16-deep unrolled
// W float4 loads for MLP. Arithmetic bit-identical to the R3 version.
// ---------------------------------------------------------------------------
__global__ __launch_bounds__(1024) void matvec_k(const float* __restrict__ W,
                                                 const float* __restrict__ x,
                                                 const float* __restrict__ b,
                                                 const float* __restrict__ c,
                                                 float* __restrict__ h,
                                                 u64* __restrict__ Kkey) {
  __shared__ float xs[N];  // 32 KiB
  const int tid = threadIdx.x;
  {
    const float4* x4 = reinterpret_cast<const float4*>(x);
    float4* xs4 = reinterpret_cast<float4*>(xs);
    xs4[tid * 2]     = x4[tid * 2];
    xs4[tid * 2 + 1] = x4[tid * 2 + 1];
  }
  __syncthreads();

  const int lane = tid & 63;
  const int wid = tid >> 6;
  const int row = blockIdx.x * 16 + wid;
  const float4* Wr = reinterpret_cast<const float4*>(W + (size_t)row * N);
  const float4* xs4 = reinterpret_cast<const float4*>(xs);
  float acc = 0.f;
#pragma unroll 16
  for (int k = 0; k < 32; ++k) {
    const int i = k * 64 + lane;
    const float4 w = Wr[i];
    const float4 xv = xs4[i];
    acc = fmaf(w.x, xv.x, acc);
    acc = fmaf(w.y, xv.y, acc);
    acc = fmaf(w.z, xv.z, acc);
    acc = fmaf(w.w, xv.w, acc);
  }
#pragma unroll
  for (int off = 32; off > 0; off >>= 1) acc += __shfl_down(acc, off, 64);
  if (lane == 0) {
    const float hv = acc + b[row];
    h[row] = hv;
    const float key = logf(c[row]) - hv;  // c==0 -> -inf, sorts first
    unsigned int u = __float_as_uint(key);
    u = (u & 0x80000000u) ? ~u : (u | 0x80000000u);  // float -> sortable uint
    Kkey[row] = ((u64)u << 13) | (unsigned int)row;  // row < 8192 = 2^13
  }
}

// ---------------------------------------------------------------------------
// Kernel B: partial ranks. Grid (32 element-groups, 8 key-chunks) x 256 thr.
// Each thread owns one element i and counts Kkey[j] < Kkey[i] over a
// 1024-key chunk. Chunk reads are wave-uniform -> scalar-cache loads.
// ---------------------------------------------------------------------------
__global__ __launch_bounds__(256) void rank_k(const u64* __restrict__ Kkey,
                                              unsigned int* __restrict__ partial) {
  const int i = blockIdx.x * 256 + threadIdx.x;
  const u64 Ki = Kkey[i];
  const u64* __restrict__ Kc = Kkey + blockIdx.y * 1024;
  unsigned int cnt = 0;
#pragma unroll 8
  for (int t = 0; t < 1024; ++t) cnt += (Kc[t] < Ki) ? 1u : 0u;
  partial[blockIdx.y * N + i] = cnt;
}

// ---------------------------------------------------------------------------
// Kernel C: budget-constrained softmax, one 1024-thread block, NO SORT.
// (verified bit-exact vs reference in R3; unchanged)
// ---------------------------------------------------------------------------
__global__ __launch_bounds__(1024) void bcsoftmax_k(const float* __restrict__ h,
                                                    const float* __restrict__ c,
                                                    const unsigned int* __restrict__ partial,
                                                    float* __restrict__ out) {
  __shared__ float hbuf[N];          // 32 KiB (reused as ybuf at the end)
  __shared__ float cbuf[N];          // 32 KiB
  __shared__ unsigned int sperm[N];  // 32 KiB: sorted pos -> original idx
  __shared__ float red[32];
  __shared__ float bcast[4];
  const int tid = threadIdx.x;
  const int lane = tid & 63;
  const int wid = tid >> 6;

  // ---- Phase 0a: coalesced stage of h, c into LDS; running max of h -------
  float lmax = -INFINITY;
  {
    const float4* h4 = reinterpret_cast<const float4*>(h);
    const float4* c4 = reinterpret_cast<const float4*>(c);
    const float4 a0 = h4[tid * 2], a1 = h4[tid * 2 + 1];
    const float4 b0 = c4[tid * 2], b1 = c4[tid * 2 + 1];
    reinterpret_cast<float4*>(hbuf)[tid * 2]     = a0;
    reinterpret_cast<float4*>(hbuf)[tid * 2 + 1] = a1;
    reinterpret_cast<float4*>(cbuf)[tid * 2]     = b0;
    reinterpret_cast<float4*>(cbuf)[tid * 2 + 1] = b1;
    lmax = fmaxf(lmax, fmaxf(fmaxf(a0.x, a0.y), fmaxf(a0.z, a0.w)));
    lmax = fmaxf(lmax, fmaxf(fmaxf(a1.x, a1.y), fmaxf(a1.z, a1.w)));
  }
#pragma unroll
  for (int off = 32; off > 0; off >>= 1) lmax = fmaxf(lmax, __shfl_down(lmax, off, 64));
  if (lane == 0) red[wid] = lmax;

  // ---- Phase 0b: sum rank partials, scatter permutation into LDS ----------
#pragma unroll
  for (int p = 0; p < 8; ++p) {
    const int g = p * 1024 + tid;  // coalesced ownership for partial reads
    unsigned int rank = 0;
#pragma unroll
    for (int y = 0; y < 8; ++y) rank += partial[y * N + g];
    sperm[rank] = (unsigned int)g;
  }
  __syncthreads();  // hbuf, cbuf, sperm, red all visible
  if (tid == 0) {
    float mm = red[0];
    for (int i = 1; i < 16; ++i) mm = fmaxf(mm, red[i]);
    bcast[0] = mm;
  }
  __syncthreads();
  const float M = bcast[0];

  // ---- Phase C: gather sorted xs, cs from LDS; chunk totals ---------------
  int idx[8];
  float xs[8], cs[8], e[8];
  float cloc = 0.f, eloc = 0.f;
  {
    const uint4* sp4 = reinterpret_cast<const uint4*>(sperm);
    const uint4 i0 = sp4[tid * 2], i1 = sp4[tid * 2 + 1];
    idx[0] = i0.x; idx[1] = i0.y; idx[2] = i0.z; idx[3] = i0.w;
    idx[4] = i1.x; idx[5] = i1.y; idx[6] = i1.z; idx[7] = i1.w;
  }
#pragma unroll
  for (int p = 0; p < 8; ++p) {
    xs[p] = hbuf[idx[p]];
    cs[p] = cbuf[idx[p]];
  }
#pragma unroll
  for (int p = 0; p < 8; ++p) {
    e[p] = expf(xs[p] - M);
    cloc += cs[p];
    eloc += e[p];
  }

  // ---- Phase D: block scans via shuffles ----------------------------------
  float cinc = cloc;
#pragma unroll
  for (int off = 1; off < 64; off <<= 1) {
    const float t = __shfl_up(cinc, off, 64);
    if (lane >= off) cinc += t;
  }
  float cwex = __shfl_up(cinc, 1, 64);
  if (lane == 0) cwex = 0.f;
  __syncthreads();  // red reuse (was lmax partials)
  if (lane == 63) red[wid] = cinc;  // wave totals
  __syncthreads();
  if (tid < 16) {
    float winc = red[tid];
#pragma unroll
    for (int off = 1; off < 16; off <<= 1) {
      const float t = __shfl_up(winc, off, 64);
      if (lane >= off) winc += t;
    }
    float wexc = __shfl_up(winc, 1, 64);
    if (tid == 0) wexc = 0.f;
    red[tid] = wexc;
  }
  __syncthreads();
  const float cthread_excl = red[wid] + cwex;

  float sinc = eloc;
#pragma unroll
  for (int off = 1; off < 64; off <<= 1) {
    const float t = __shfl_down(sinc, off, 64);
    if (lane + off < 64) sinc += t;
  }
  float swex = __shfl_down(sinc, 1, 64);
  if (lane == 63) swex = 0.f;
  __syncthreads();
  if (lane == 0) red[16 + wid] = sinc;  // wave suffix totals
  __syncthreads();
  if (tid < 16) {
    float winc = red[16 + tid];
#pragma unroll
    for (int off = 1; off < 16; off <<= 1) {
      const float t = __shfl_down(winc, off, 64);
      if (tid + off < 16) winc += t;
    }
    float wexc = __shfl_down(winc, 1, 64);
    if (tid == 15) wexc = 0.f;
    red[16 + tid] = wexc;
  }
  __syncthreads();
  const float ethread_exsuf = red[16 + wid] + swex;

  // ---- Phase E: membership predicate + reductions -------------------------
  float lsuf[8];
  lsuf[7] = e[7];
#pragma unroll
  for (int p = 6; p >= 0; --p) lsuf[p] = e[p] + lsuf[p + 1];
  float cexc = 0.f;
  bool kb[8];
  float lm = -INFINITY, lkbc = 0.f;
#pragma unroll
  for (int p = 0; p < 8; ++p) {
    const float s = 1.0f - (cthread_excl + cexc);
    const float suff = ethread_exsuf + lsuf[p];
    const float log_r = M + logf(suff);
    const bool in_kb =
        (cs[p] == 0.0f) ||
        ((s - cs[p] > 0.0f) && (xs[p] - log_r + logf(s) > logf(cs[p])));
    kb[p] = in_kb;
    if (in_kb) lkbc += cs[p];
    else       lm = fmaxf(lm, xs[p]);
    cexc += cs[p];
  }
#pragma unroll
  for (int off = 32; off > 0; off >>= 1) {
    lm = fmaxf(lm, __shfl_down(lm, off, 64));
    lkbc += __shfl_down(lkbc, off, 64);
  }
  __syncthreads();
  if (lane == 0) { red[wid] = lm; red[16 + wid] = lkbc; }
  __syncthreads();
  if (tid == 0) {
    float mm = red[0], sc = red[16];
    for (int i = 1; i < 16; ++i) { mm = fmaxf(mm, red[i]); sc += red[16 + i]; }
    bcast[1] = mm;
    bcast[2] = 1.0f - sc;  // s2
  }
  __syncthreads();
  const float m = bcast[1];
  const float s2 = bcast[2];

  float ey[8];
  float lr = 0.f;
#pragma unroll
  for (int p = 0; p < 8; ++p) {
    ey[p] = expf(xs[p] - m);
    if (!kb[p]) lr += ey[p];
  }
#pragma unroll
  for (int off = 32; off > 0; off >>= 1) lr += __shfl_down(lr, off, 64);
  if (lane == 0) red[wid] = lr;
  __syncthreads();
  if (tid == 0) {
    float rr = red[0];
    for (int i = 1; i < 16; ++i) rr += red[i];
    bcast[3] = rr;
  }
  __syncthreads();
  const float r = bcast[3];

  // ---- Phase F: scatter to LDS, then coalesced global store ---------------
  float* ybuf = hbuf;  // hbuf no longer needed
#pragma unroll
  for (int p = 0; p < 8; ++p) {
    ybuf[idx[p]] = kb[p] ? cs[p] : s2 * ey[p] / r;
  }
  __syncthreads();
  {
    const float4* y4 = reinterpret_cast<const float4*>(ybuf);
    float4* o4 = reinterpret_cast<float4*>(out);
    o4[tid * 2]     = y4[tid * 2];
    o4[tid * 2 + 1] = y4[tid * 2 + 1];
  }
}

// ---------------------------------------------------------------------------
extern "C" void kernel_launch(void* const* d_in, const int* in_sizes, int n_in,
                              void* d_out, int out_size, void* d_ws, size_t ws_size,
                              hipStream_t stream) {
  (void)in_sizes; (void)n_in; (void)out_size; (void)ws_size;
  const float* x = (const float*)d_in[0];
  const float* c = (const float*)d_in[1];
  const float* W = (const float*)d_in[2];
  const float* b = (const float*)d_in[3];
  float* out = (float*)d_out;

  // ws layout: h (32 KB) | Kkey (64 KB) | partial (256 KB)
  char* ws = (char*)d_ws;
  float* h = (float*)ws;
  u64* Kkey = (u64*)(ws + 32768);
  unsigned int* partial = (unsigned int*)(ws + 32768 + 65536);

  matvec_k<<<N / 16, 1024, 0, stream>>>(W, x, b, c, h, Kkey);
  rank_k<<<dim3(32, 8), 256, 0, stream>>>(Kkey, partial);
  bcsoftmax_k<<<1, 1024, 0, stream>>>(h, c, partial, out);
}